// Round 9
// baseline (32.384 us; speedup 1.0000x reference)
//
#include <hip/hip_runtime.h>
#include <cmath>

// KFIoU loss: pred (NP x 5), target (NT x 5) -> loss (NP x NT) f32.
//
// Numerics (established R1-R5): the harness's "np" reference is a FLOAT32
// numpy evaluation of the cancellation-heavy Sigma = P - K*P chain. We
// reproduce its fp32 noise bit-for-bit: identical op order, no fma
// contraction, correctly-rounded f32 div/sqrt (__fdiv_rn/__fsqrt_rn),
// correctly-rounded f32 sin/cos (evaluated in double, rounded to f32).
// Residual absmax 0.0117 (< 2e-2) comes from numpy's non-CR SIMD sinf —
// irreducible without bit-matching numpy's polynomial. Pair math here is
// BIT-IDENTICAL to R5-R8 (regression check: absmax == 0.01171875).
//
// Perf (this round): occupancy repair. R8's packed v2f doubled live VGPRs
// under the 64-VGPR cap of __launch_bounds__(256,8) -> likely scratch
// spills; R5/R6 uncapped -> ~4 waves/SIMD. This version: scalar
// one-pair-per-iteration loop, ~30 live VGPRs (pred params come in via
// wave-uniform s_load -> SGPRs), guaranteed spill-free 8 waves/SIMD.
// CR divide chains are VCC-serialized within a wave, so TLP (8 waves) is
// the only latency-hiding mechanism -> occupancy is everything.

constexpr int ROWS = 16;   // pred rows per block tile
constexpr int COLS = 256;  // target cols per block (= blockDim.x)

// ---------------- kernel A: per-box params (s00, s01, s11, Vb) ------------
__global__ __launch_bounds__(256) void box_param_kernel(
    const float* __restrict__ pred, int np,
    const float* __restrict__ target, int nt,
    float4* __restrict__ ws) {
#pragma clang fp contract(off)
  int i = blockIdx.x * 256 + threadIdx.x;
  int n = np + nt;
  if (i >= n) return;
  const float* bx = (i < np) ? (pred + (size_t)i * 5)
                             : (target + (size_t)(i - np) * 5);
  float w = fminf(fmaxf(bx[2], 1e-7f), 1e7f);
  float h = fminf(fmaxf(bx[3], 1e-7f), 1e7f);
  float r = bx[4];
  // correctly-rounded f32 sin/cos via double evaluation (matches numpy)
  float s = (float)sin((double)r);
  float c = (float)cos((double)r);
  float a = (0.5f * w) * (0.5f * w);
  float b = (0.5f * h) * (0.5f * h);
  float s00 = a * c * c + b * s * s;
  float s01 = (a - b) * s * c;
  float s11 = a * s * s + b * c * c;
  float det = s00 * s11 - s01 * s01;
  float vb  = 4.0f * __fsqrt_rn(fabsf(det));
  ws[i] = make_float4(s00, s01, s11, vb);
}

// ---------------- kernel B: pair loss (scalar, minimal liveness) ----------
__device__ __forceinline__ float kf_pair(float4 p, float4 t) {
#pragma clang fp contract(off)
  float m00 = p.x + t.x;
  float m01 = p.y + t.y;
  float m11 = p.z + t.z;
  float det_m = m00 * m11 - m01 * m01;
  float i00 = __fdiv_rn(m11, det_m);
  float i01 = __fdiv_rn(-m01, det_m);
  float i11 = __fdiv_rn(m00, det_m);
  float k00 = p.x * i00 + p.y * i01;
  float k01 = p.x * i01 + p.y * i11;
  float k10 = p.y * i00 + p.z * i01;
  float k11 = p.y * i01 + p.z * i11;
  float sig00 = p.x - (k00 * p.x + k01 * p.y);
  float sig01 = p.y - (k00 * p.y + k01 * p.z);
  float sig10 = p.y - (k10 * p.x + k11 * p.y);
  float sig11 = p.z - (k10 * p.y + k11 * p.z);
  float det_sig = sig00 * sig11 - sig01 * sig10;
  float vb = 4.0f * __fsqrt_rn(fabsf(det_sig));
  float denom = p.w + t.w - vb + 1e-6f;
  float kf = __fdiv_rn(vb, denom);
  return fmaxf(1.0f - kf, 0.0f);
}

__global__ __launch_bounds__(256, 8) void kf_loss_kernel(
    const float4* __restrict__ pp,   // np pred params
    const float4* __restrict__ tp,   // nt target params
    float* __restrict__ out, int np, int nt) {
  const int col  = blockIdx.y * COLS + threadIdx.x;
  const int row0 = blockIdx.x * ROWS;
  if (col >= nt) return;

  const float4 t = tp[col];          // 4 VGPR, held for the whole kernel

  int rend = ROWS;
  if (row0 + rend > np) rend = np - row0;
  float* o = out + (size_t)row0 * (size_t)nt + col;

  for (int rr = 0; rr < rend; ++rr) {
    float4 p = pp[row0 + rr];        // wave-uniform -> s_load_dwordx4
    *o = kf_pair(p, t);
    o += nt;                         // incremental addressing, no 64b mul
  }
}

extern "C" void kernel_launch(void* const* d_in, const int* in_sizes, int n_in,
                              void* d_out, int out_size, void* d_ws, size_t ws_size,
                              hipStream_t stream) {
  const float* pred   = (const float*)d_in[0];
  const float* target = (const float*)d_in[1];
  float* out = (float*)d_out;
  int np = in_sizes[0] / 5;
  int nt = in_sizes[1] / 5;

  float4* params = (float4*)d_ws;           // np + nt entries
  int nbox = np + nt;
  box_param_kernel<<<(nbox + 255) / 256, 256, 0, stream>>>(
      pred, np, target, nt, params);

  dim3 grid((np + ROWS - 1) / ROWS, (nt + COLS - 1) / COLS);
  kf_loss_kernel<<<grid, dim3(COLS), 0, stream>>>(
      params, params + np, out, np, nt);
}

// Round 10
// 23.532 us; speedup vs baseline: 1.3762x; 1.3762x over previous
//
#include <hip/hip_runtime.h>
#include <cmath>

// KFIoU loss: pred (NP x 5), target (NT x 5) -> loss (NP x NT) f32.
//
// Numerics (established R1-R9): harness ref is a FLOAT32 numpy evaluation.
// Bit-faithfulness recipe: identical op order, no fma contraction in the
// mul/add chain, correctly-rounded f32 sin/cos (via double in kernel A).
// THIS round replaces stock CR div/sqrt with hand-rolled equivalents:
//  - 3 matrix divides share ONE refined reciprocal (rcp + Newton) +
//    Markstein fma correction each -> faithful, ~0.4 expected 1-ulp
//    misrounds over 25M divides (same class as sin/cos ulp noise).
//  - raw v_sqrt_f32 (1 ulp): det_sig cancellation is UPSTREAM of sqrt,
//    denom has NO cancellation (Vb <= (Vp+Vt)/3) -> no amplification.
//  - final kf divide via refined rcp.
// Data ranges (clip 1e-7, uniform inputs): det_m in [~1e-29, 1] -> normal,
// no overflow in q = a*r (<= 5e28) -> div_scale machinery unnecessary.

typedef float v2f __attribute__((ext_vector_type(2)));

constexpr int ROWS = 16;   // pred rows per block tile (2 per iteration)
constexpr int COLS = 256;  // target cols per block (= blockDim.x)

// ---------------- kernel A: per-box params (s00, s01, s11, Vb) ------------
__global__ __launch_bounds__(256) void box_param_kernel(
    const float* __restrict__ pred, int np,
    const float* __restrict__ target, int nt,
    float4* __restrict__ ws) {
#pragma clang fp contract(off)
  int i = blockIdx.x * 256 + threadIdx.x;
  int n = np + nt;
  if (i >= n) return;
  const float* bx = (i < np) ? (pred + (size_t)i * 5)
                             : (target + (size_t)(i - np) * 5);
  float w = fminf(fmaxf(bx[2], 1e-7f), 1e7f);
  float h = fminf(fmaxf(bx[3], 1e-7f), 1e7f);
  float r = bx[4];
  // correctly-rounded f32 sin/cos via double evaluation (matches numpy)
  float s = (float)sin((double)r);
  float c = (float)cos((double)r);
  float a = (0.5f * w) * (0.5f * w);
  float b = (0.5f * h) * (0.5f * h);
  float s00 = a * c * c + b * s * s;
  float s01 = (a - b) * s * c;
  float s11 = a * s * s + b * c * c;
  float det = s00 * s11 - s01 * s01;
  float vb  = 4.0f * __fsqrt_rn(fabsf(det));
  ws[i] = make_float4(s00, s01, s11, vb);
}

// ---------------- fast faithful division helpers --------------------------
__device__ __forceinline__ v2f rcp_refined(v2f d) {
  v2f r;
  r[0] = __builtin_amdgcn_rcpf(d[0]);
  r[1] = __builtin_amdgcn_rcpf(d[1]);
  v2f one = {1.0f, 1.0f};
  v2f e = __builtin_elementwise_fma(-d, r, one);   // 1 - d*r
  return __builtin_elementwise_fma(e, r, r);       // r*(2 - d*r)
}

__device__ __forceinline__ v2f div_faithful(v2f a, v2f d, v2f r) {
  v2f q = a * r;                                   // pk_mul
  v2f e = __builtin_elementwise_fma(-d, q, a);     // residual
  return __builtin_elementwise_fma(e, r, q);       // Markstein correction
}

// ---------------- kernel B: pair loss, 2 rows per call (packed f32) -------
__device__ __forceinline__ v2f kf_pair2(float4 p0, float4 p1, float4 t) {
#pragma clang fp contract(off)
  v2f px = {p0.x, p1.x};
  v2f py = {p0.y, p1.y};
  v2f pz = {p0.z, p1.z};
  v2f pw = {p0.w, p1.w};

  v2f m00 = px + t.x;
  v2f m01 = py + t.y;
  v2f m11 = pz + t.z;
  v2f det_m = m00 * m11 - m01 * m01;   // separate mul/sub (contract off)

  v2f r = rcp_refined(det_m);
  v2f i00 = div_faithful(m11, det_m, r);
  v2f i01 = div_faithful(-m01, det_m, r);
  v2f i11 = div_faithful(m00, det_m, r);

  v2f k00 = px * i00 + py * i01;
  v2f k01 = px * i01 + py * i11;
  v2f k10 = py * i00 + pz * i01;
  v2f k11 = py * i01 + pz * i11;

  v2f sig00 = px - (k00 * px + k01 * py);
  v2f sig01 = py - (k00 * py + k01 * pz);
  v2f sig10 = py - (k10 * px + k11 * py);
  v2f sig11 = pz - (k10 * py + k11 * pz);

  v2f det_sig = sig00 * sig11 - sig01 * sig10;
  v2f vb;
  vb[0] = 4.0f * __builtin_amdgcn_sqrtf(fabsf(det_sig[0]));
  vb[1] = 4.0f * __builtin_amdgcn_sqrtf(fabsf(det_sig[1]));

  v2f denom = pw + t.w - vb + 1e-6f;   // left-assoc; no cancellation here
  v2f rd = rcp_refined(denom);
  v2f kf = div_faithful(vb, denom, rd);

  v2f one = {1.0f, 1.0f};
  v2f zero = {0.0f, 0.0f};
  v2f res = one - kf;
  res[0] = fmaxf(res[0], zero[0]);
  res[1] = fmaxf(res[1], zero[1]);
  return res;
}

__global__ __launch_bounds__(256, 8) void kf_loss_kernel(
    const float4* __restrict__ pp,   // np pred params
    const float4* __restrict__ tp,   // nt target params
    float* __restrict__ out, int np, int nt) {
  const int col  = blockIdx.y * COLS + threadIdx.x;
  const int row0 = blockIdx.x * ROWS;
  if (col >= nt) return;

  const float4 t = tp[col];          // 4 VGPR, held for the whole kernel

  for (int rr = 0; rr < ROWS; rr += 2) {
    int r0 = row0 + rr;
    int r1 = r0 + 1;
    int r0c = (r0 < np) ? r0 : (np - 1);
    int r1c = (r1 < np) ? r1 : (np - 1);
    float4 p0 = pp[r0c];             // wave-uniform -> scalar loads
    float4 p1 = pp[r1c];
    v2f o = kf_pair2(p0, p1, t);
    if (r0 < np) out[(size_t)r0 * (size_t)nt + col] = o[0];
    if (r1 < np) out[(size_t)r1 * (size_t)nt + col] = o[1];
  }
}

extern "C" void kernel_launch(void* const* d_in, const int* in_sizes, int n_in,
                              void* d_out, int out_size, void* d_ws, size_t ws_size,
                              hipStream_t stream) {
  const float* pred   = (const float*)d_in[0];
  const float* target = (const float*)d_in[1];
  float* out = (float*)d_out;
  int np = in_sizes[0] / 5;
  int nt = in_sizes[1] / 5;

  float4* params = (float4*)d_ws;           // np + nt entries
  int nbox = np + nt;
  box_param_kernel<<<(nbox + 255) / 256, 256, 0, stream>>>(
      pred, np, target, nt, params);

  dim3 grid((np + ROWS - 1) / ROWS, (nt + COLS - 1) / COLS);
  kf_loss_kernel<<<grid, dim3(COLS), 0, stream>>>(
      params, params + np, out, np, nt);
}